// Round 5
// baseline (3797.631 us; speedup 1.0000x reference)
//
#include <hip/hip_runtime.h>

#define BSZ  2048
#define TLEN 512
#define HDIM 64
#define NG   256   // 4*H gate rows
#define NB   8     // batch rows per block
#define NTH  768   // 3 groups x 256 gate rows
#define GRID (BSZ / NB)   // 256 blocks = 1 per CU

__device__ __forceinline__ float sigm(float x) {
    return __fdividef(1.0f, 1.0f + __expf(-x));
}
__device__ __forceinline__ float tanh_(float x) {
    return 1.0f - __fdividef(2.0f, __expf(2.0f * x) + 1.0f);
}

// 12 waves/block, 1 block/CU -> 3 waves/EU -> VGPR cap ~170; demand ~130
__global__ __launch_bounds__(NTH, 3)
void lstm2_fused(const float* __restrict__ x,
                 const float* __restrict__ w_ih0,
                 const float* __restrict__ w_hh0,
                 const float* __restrict__ b_ih0,
                 const float* __restrict__ b_hh0,
                 const float* __restrict__ w_ih1,
                 const float* __restrict__ w_hh1,
                 const float* __restrict__ b_ih1,
                 const float* __restrict__ b_hh1,
                 const float* __restrict__ fc_w,
                 const float* __restrict__ fc_b,
                 float* __restrict__ out)
{
    __shared__ float xs[NB][TLEN];     // 16 KB staged input
    __shared__ float gs[3][NB][NG];    // 24 KB gate (partial) pre-activations
    __shared__ float h1s[NB][HDIM];    //  2 KB layer-0 hidden
    __shared__ float h2s[NB][HDIM];    //  2 KB layer-1 hidden

    const int tid = threadIdx.x;
    const int g   = tid >> 8;          // matrix group 0/1/2 (wave-uniform)
    const int j   = tid & 255;         // gate row
    const int b0  = blockIdx.x * NB;

    // ---- stage x rows as float4 (coalesced) ----
    {
        const float4* xg = (const float4*)(x + (size_t)b0 * TLEN);
        for (int idx = tid; idx < NB * TLEN / 4; idx += NTH) {
            const int row = idx >> 7;          // / (TLEN/4)
            const int col = idx & 127;
            ((float4*)&xs[row][0])[col] = xg[row * 128 + col];
        }
    }
    if (tid < NB * HDIM) {
        h1s[tid >> 6][tid & 63] = 0.0f;
        h2s[tid >> 6][tid & 63] = 0.0f;
    }

    // ---- one 64-wide weight row per thread, strictly register-resident ----
    // No address-of on w[]: constant indices only, so SROA promotes fully.
    const float* wrow = (g == 0) ? (w_hh0 + j * HDIM)
                      : (g == 1) ? (w_ih1 + j * HDIM)
                                 : (w_hh1 + j * HDIM);
    float w[HDIM];
    #pragma unroll
    for (int c = 0; c < 16; ++c) {
        const float4 v = ((const float4*)wrow)[c];
        w[4*c + 0] = v.x; w[4*c + 1] = v.y; w[4*c + 2] = v.z; w[4*c + 3] = v.w;
    }
    const float wih0j = w_ih0[j];                       // used by g0 only
    const float bias0 = b_ih0[j] + b_hh0[j];            // used by g0 only

    // compute-phase source / destination (wave-uniform pointers)
    const float* hp = (g == 2) ? &h2s[0][0] : &h1s[0][0];
    float*       gp = &gs[g][0][0];

    // update-phase ownership
    const int ub1 = (tid >> 6) & 7, uk1 = tid & 63;     // c1 owner: tid < 512
    const int p2  = tid - 256;
    const int ub2 = (p2 >> 6) & 7, uk2 = p2 & 63;       // c2 owner: tid >= 256
    float b1i = 0.f, b1f = 0.f, b1g = 0.f, b1o = 0.f;
    if (tid >= 256) {
        b1i = b_ih1[uk2      ] + b_hh1[uk2      ];
        b1f = b_ih1[uk2 +  64] + b_hh1[uk2 +  64];
        b1g = b_ih1[uk2 + 128] + b_hh1[uk2 + 128];
        b1o = b_ih1[uk2 + 192] + b_hh1[uk2 + 192];
    }
    float c1 = 0.0f, c2 = 0.0f;

    __syncthreads();

    // layer-1 runs one step behind layer-0: iteration i computes
    // L0 gates(step i) and L1 gates(step i-1); both read stable state.
    for (int i = 0; i <= TLEN; ++i) {
        const bool active = (g == 0) ? (i < TLEN) : (i > 0);
        if (active) {
            float a[NB];
            #pragma unroll
            for (int b = 0; b < NB; ++b)
                a[b] = (g == 0) ? fmaf(xs[b][i], wih0j, bias0) : 0.0f;
            #pragma unroll
            for (int c = 0; c < 16; ++c) {
                #pragma unroll
                for (int b = 0; b < NB; ++b) {
                    const float4 hv = ((const float4*)(hp + b * HDIM))[c];
                    a[b] = fmaf(w[4*c + 0], hv.x, a[b]);
                    a[b] = fmaf(w[4*c + 1], hv.y, a[b]);
                    a[b] = fmaf(w[4*c + 2], hv.z, a[b]);
                    a[b] = fmaf(w[4*c + 3], hv.w, a[b]);
                }
            }
            #pragma unroll
            for (int b = 0; b < NB; ++b)
                gp[b * NG + j] = a[b];
        }
        __syncthreads();

        // ---- layer-0 state update (step i) ----
        if (tid < NB * HDIM && i < TLEN) {
            const float gi = sigm (gs[0][ub1][      uk1]);
            const float gf = sigm (gs[0][ub1][ 64 + uk1]);
            const float gg = tanh_(gs[0][ub1][128 + uk1]);
            const float go = sigm (gs[0][ub1][192 + uk1]);
            c1 = fmaf(gf, c1, gi * gg);
            h1s[ub1][uk1] = go * tanh_(c1);
        }
        // ---- layer-1 state update (step i-1) ----
        if (tid >= 256 && i > 0) {
            const float gi = sigm (gs[1][ub2][      uk2] + gs[2][ub2][      uk2] + b1i);
            const float gf = sigm (gs[1][ub2][ 64 + uk2] + gs[2][ub2][ 64 + uk2] + b1f);
            const float gg = tanh_(gs[1][ub2][128 + uk2] + gs[2][ub2][128 + uk2] + b1g);
            const float go = sigm (gs[1][ub2][192 + uk2] + gs[2][ub2][192 + uk2] + b1o);
            c2 = fmaf(gf, c2, gi * gg);
            h2s[ub2][uk2] = go * tanh_(c2);
        }
        __syncthreads();
    }

    // ---- final FC on last h2 ----
    if (tid < NB) {
        float s = fc_b[0];
        #pragma unroll
        for (int k = 0; k < HDIM; ++k)
            s = fmaf(fc_w[k], h2s[tid][k], s);
        out[b0 + tid] = s;
    }
}

extern "C" void kernel_launch(void* const* d_in, const int* in_sizes, int n_in,
                              void* d_out, int out_size, void* d_ws, size_t ws_size,
                              hipStream_t stream) {
    const float* xp     = (const float*)d_in[0];
    const float* w_ih0  = (const float*)d_in[1];
    const float* w_hh0  = (const float*)d_in[2];
    const float* b_ih0  = (const float*)d_in[3];
    const float* b_hh0  = (const float*)d_in[4];
    const float* w_ih1  = (const float*)d_in[5];
    const float* w_hh1  = (const float*)d_in[6];
    const float* b_ih1  = (const float*)d_in[7];
    const float* b_hh1  = (const float*)d_in[8];
    const float* fc_w   = (const float*)d_in[9];
    const float* fc_b   = (const float*)d_in[10];
    float* outp = (float*)d_out;

    lstm2_fused<<<dim3(GRID), dim3(NTH), 0, stream>>>(
        xp, w_ih0, w_hh0, b_ih0, b_hh0,
        w_ih1, w_hh1, b_ih1, b_hh1, fc_w, fc_b, outp);
}

// Round 6
// 3722.490 us; speedup vs baseline: 1.0202x; 1.0202x over previous
//
#include <hip/hip_runtime.h>

#define BSZ  2048
#define TLEN 512
#define HDIM 64
#define NG   256   // 4*H gate rows
#define NB   8     // batch rows per block
#define NTH  768   // 3 groups x 256 gate rows
#define GRID (BSZ / NB)   // 256 blocks = 1 per CU

__device__ __forceinline__ float sigm(float x) {
    return __fdividef(1.0f, 1.0f + __expf(-x));
}
__device__ __forceinline__ float tanh_(float x) {
    return 1.0f - __fdividef(2.0f, __expf(2.0f * x) + 1.0f);
}

// 12 waves/block, 1 block/CU -> 3 waves/EU -> VGPR cap ~168; demand ~115
__global__ __launch_bounds__(NTH, 3)
void lstm2_fused(const float* __restrict__ x,
                 const float* __restrict__ w_ih0,
                 const float* __restrict__ w_hh0,
                 const float* __restrict__ b_ih0,
                 const float* __restrict__ b_hh0,
                 const float* __restrict__ w_ih1,
                 const float* __restrict__ w_hh1,
                 const float* __restrict__ b_ih1,
                 const float* __restrict__ b_hh1,
                 const float* __restrict__ fc_w,
                 const float* __restrict__ fc_b,
                 float* __restrict__ out)
{
    __shared__ float xs[NB][TLEN];     // 16 KB staged input
    __shared__ float gs[3][NB][NG];    // 24 KB gate (partial) pre-activations
    __shared__ float h1s[NB][HDIM];    //  2 KB layer-0 hidden
    __shared__ float h2s[NB][HDIM];    //  2 KB layer-1 hidden

    const int tid = threadIdx.x;
    const int g   = tid >> 8;          // matrix group 0/1/2 (wave-uniform)
    const int j   = tid & 255;         // gate row
    const int b0  = blockIdx.x * NB;

    // ---- stage x rows as float4 (coalesced) ----
    {
        const float4* xg = (const float4*)(x + (size_t)b0 * TLEN);
        for (int idx = tid; idx < NB * TLEN / 4; idx += NTH) {
            const int row = idx >> 7;          // / (TLEN/4)
            const int col = idx & 127;
            ((float4*)&xs[row][0])[col] = xg[row * 128 + col];
        }
    }
    if (tid < NB * HDIM) {
        h1s[tid >> 6][tid & 63] = 0.0f;
        h2s[tid >> 6][tid & 63] = 0.0f;
    }

    // ---- one 64-wide weight row per thread ----
    const float* wrow = (g == 0) ? (w_hh0 + j * HDIM)
                      : (g == 1) ? (w_ih1 + j * HDIM)
                                 : (w_hh1 + j * HDIM);
    float w[HDIM];
    #pragma unroll
    for (int c = 0; c < 16; ++c) {
        const float4 v = ((const float4*)wrow)[c];
        w[4*c + 0] = v.x; w[4*c + 1] = v.y; w[4*c + 2] = v.z; w[4*c + 3] = v.w;
    }
    // PIN: make weight values opaque so the compiler cannot rematerialize
    // the global loads inside the t-loop (round-5 disease: VGPR=56, weights
    // re-loaded from L2 every step). Opaque values must stay VGPR-resident.
    #pragma unroll
    for (int k = 0; k < HDIM; ++k)
        asm volatile("" : "+v"(w[k]));

    const float wih0j = w_ih0[j];
    const float bias0 = b_ih0[j] + b_hh0[j];
    const float xmulj = (g == 0) ? wih0j : 0.0f;   // g1/g2: dead FMA, no branch
    const float base  = (g == 0) ? bias0 : 0.0f;

    // compute-phase source / destination (wave-uniform pointers)
    const float* hp = (g == 2) ? &h2s[0][0] : &h1s[0][0];
    float*       gp = &gs[g][0][0];

    // update-phase ownership
    const int ub1 = (tid >> 6) & 7, uk1 = tid & 63;     // c1 owner: tid < 512
    const int p2  = tid - 256;
    const int ub2 = (p2 >> 6) & 7, uk2 = p2 & 63;       // c2 owner: tid >= 256
    float b1i = 0.f, b1f = 0.f, b1g = 0.f, b1o = 0.f;
    if (tid >= 256) {
        b1i = b_ih1[uk2      ] + b_hh1[uk2      ];
        b1f = b_ih1[uk2 +  64] + b_hh1[uk2 +  64];
        b1g = b_ih1[uk2 + 128] + b_hh1[uk2 + 128];
        b1o = b_ih1[uk2 + 192] + b_hh1[uk2 + 192];
    }
    float c1 = 0.0f, c2 = 0.0f;

    __syncthreads();

    // layer-1 runs one step behind layer-0: iteration i computes
    // L0 gates(step i) and L1 gates(step i-1); both read stable state.
    for (int i = 0; i <= TLEN; ++i) {
        const bool active = (g == 0) ? (i < TLEN) : (i > 0);
        if (active) {
            float a[NB];
            #pragma unroll
            for (int b = 0; b < NB; ++b)
                a[b] = fmaf(xs[b][i], xmulj, base);
            #pragma unroll
            for (int c = 0; c < 16; ++c) {
                #pragma unroll
                for (int b = 0; b < NB; ++b) {
                    const float4 hv = ((const float4*)(hp + b * HDIM))[c];
                    a[b] = fmaf(w[4*c + 0], hv.x, a[b]);
                    a[b] = fmaf(w[4*c + 1], hv.y, a[b]);
                    a[b] = fmaf(w[4*c + 2], hv.z, a[b]);
                    a[b] = fmaf(w[4*c + 3], hv.w, a[b]);
                }
            }
            #pragma unroll
            for (int b = 0; b < NB; ++b)
                gp[b * NG + j] = a[b];
        }
        __syncthreads();

        // ---- layer-0 state update (step i) ----
        if (tid < NB * HDIM && i < TLEN) {
            const float gi = sigm (gs[0][ub1][      uk1]);
            const float gf = sigm (gs[0][ub1][ 64 + uk1]);
            const float gg = tanh_(gs[0][ub1][128 + uk1]);
            const float go = sigm (gs[0][ub1][192 + uk1]);
            c1 = fmaf(gf, c1, gi * gg);
            h1s[ub1][uk1] = go * tanh_(c1);
        }
        // ---- layer-1 state update (step i-1) ----
        if (tid >= 256 && i > 0) {
            const float gi = sigm (gs[1][ub2][      uk2] + gs[2][ub2][      uk2] + b1i);
            const float gf = sigm (gs[1][ub2][ 64 + uk2] + gs[2][ub2][ 64 + uk2] + b1f);
            const float gg = tanh_(gs[1][ub2][128 + uk2] + gs[2][ub2][128 + uk2] + b1g);
            const float go = sigm (gs[1][ub2][192 + uk2] + gs[2][ub2][192 + uk2] + b1o);
            c2 = fmaf(gf, c2, gi * gg);
            h2s[ub2][uk2] = go * tanh_(c2);
        }
        __syncthreads();
    }

    // ---- final FC on last h2 ----
    if (tid < NB) {
        float s = fc_b[0];
        #pragma unroll
        for (int k = 0; k < HDIM; ++k)
            s = fmaf(fc_w[k], h2s[tid][k], s);
        out[b0 + tid] = s;
    }
}

extern "C" void kernel_launch(void* const* d_in, const int* in_sizes, int n_in,
                              void* d_out, int out_size, void* d_ws, size_t ws_size,
                              hipStream_t stream) {
    const float* xp     = (const float*)d_in[0];
    const float* w_ih0  = (const float*)d_in[1];
    const float* w_hh0  = (const float*)d_in[2];
    const float* b_ih0  = (const float*)d_in[3];
    const float* b_hh0  = (const float*)d_in[4];
    const float* w_ih1  = (const float*)d_in[5];
    const float* w_hh1  = (const float*)d_in[6];
    const float* b_ih1  = (const float*)d_in[7];
    const float* b_hh1  = (const float*)d_in[8];
    const float* fc_w   = (const float*)d_in[9];
    const float* fc_b   = (const float*)d_in[10];
    float* outp = (float*)d_out;

    lstm2_fused<<<dim3(GRID), dim3(NTH), 0, stream>>>(
        xp, w_ih0, w_hh0, b_ih0, b_hh0,
        w_ih1, w_hh1, b_ih1, b_hh1, fc_w, fc_b, outp);
}

// Round 7
// 944.199 us; speedup vs baseline: 4.0221x; 3.9425x over previous
//
#include <hip/hip_runtime.h>

#define TLEN 512
#define HDIM 64
#define NB   8     // batches per block
#define NTH  512   // 8 waves
#define GRID 256   // 2048 / NB = 1 block per CU

typedef __attribute__((ext_vector_type(8))) short bf16x8;
typedef __attribute__((ext_vector_type(4))) float f32x4;

__device__ __forceinline__ float sigm(float x){ return __fdividef(1.f, 1.f+__expf(-x)); }
__device__ __forceinline__ float tanh_(float x){ return 1.f - __fdividef(2.f, __expf(2.f*x)+1.f); }

// f32 -> bf16 round-to-nearest-even (bit pattern in short)
__device__ __forceinline__ short bf16rn(float f){
    unsigned u = __float_as_uint(f);
    u = (u + 0x7FFFu + ((u >> 16) & 1u)) >> 16;
    return (short)u;
}
__device__ __forceinline__ float bf2f(short s){
    return __uint_as_float(((unsigned)(unsigned short)s) << 16);
}

// Load one 16-row x 64-k A-tile as hi/lo bf16 fragments for mfma_16x16x32.
// Lane l supplies A[l&15][khalf*32 + (l>>4)*8 + e], e=0..7.
__device__ __forceinline__ void loadA(const float* __restrict__ W, int rowbase, int lane,
                                      bf16x8& hi0, bf16x8& lo0, bf16x8& hi1, bf16x8& lo1)
{
    const int row = rowbase + (lane & 15);
    const int q   = lane >> 4;
    const float* p = W + row * HDIM + q * 8;
    #pragma unroll
    for (int e = 0; e < 8; ++e) {
        const float f0 = p[e];        // khalf0
        const float f1 = p[32 + e];   // khalf1
        const short a0 = bf16rn(f0); hi0[e] = a0; lo0[e] = bf16rn(f0 - bf2f(a0));
        const short a1 = bf16rn(f1); hi1[e] = a1; lo1[e] = bf16rn(f1 - bf2f(a1));
    }
}

__global__ __launch_bounds__(NTH, 2)
void lstm2_mfma(const float* __restrict__ x,
                const float* __restrict__ w_ih0,
                const float* __restrict__ w_hh0,
                const float* __restrict__ b_ih0,
                const float* __restrict__ b_hh0,
                const float* __restrict__ w_ih1,
                const float* __restrict__ w_hh1,
                const float* __restrict__ b_ih1,
                const float* __restrict__ b_hh1,
                const float* __restrict__ fc_w,
                const float* __restrict__ fc_b,
                float* __restrict__ out)
{
    __shared__ float xs[NB][TLEN];                     // 16 KB staged input
    __shared__ float gates[3 * 256 * 9];               // 27.6 KB  ((mat*256+row)*9 + b)
    __shared__ __align__(16) short h1hi[16][72];       // h1 hi bf16 (rows 8..15 stay 0)
    __shared__ __align__(16) short h1lo[16][72];
    __shared__ __align__(16) short h2hi[16][72];
    __shared__ __align__(16) short h2lo[16][72];
    __shared__ float h2last[NB * HDIM];                // 2 KB final-step h2 in f32

    const int tid  = threadIdx.x;
    const int wid  = tid >> 6;        // wave 0..7
    const int lane = tid & 63;
    const int q    = lane >> 4;       // fragment quad 0..3
    const int r15  = lane & 15;       // fragment row/col index
    const int b0   = blockIdx.x * NB;

    // ---- stage x (coalesced float4) ----
    {
        const float4* xg = (const float4*)(x + (size_t)b0 * TLEN);
        for (int idx = tid; idx < NB * TLEN / 4; idx += NTH) {
            const int row = idx >> 7;          // / (TLEN/4)
            const int col = idx & 127;
            ((float4*)&xs[row][0])[col] = xg[row * 128 + col];
        }
    }
    // ---- zero h state (incl. pad rows 8..15 and pad cols) ----
    for (int idx = tid; idx < 16 * 72; idx += NTH) {
        ((short*)h1hi)[idx] = 0; ((short*)h1lo)[idx] = 0;
        ((short*)h2hi)[idx] = 0; ((short*)h2lo)[idx] = 0;
    }

    // ---- A fragments (static weights), tile T = wid + 8*j ----
    // j=0,1 -> w_hh0 ; j=2,3 -> w_ih1 ; j=4,5 -> w_hh1
    // rowbase(j) = (wid + 8*(j&1)) * 16
    bf16x8 Ahi0[6], Alo0[6], Ahi1[6], Alo1[6];
    const int rb_lo = wid * 16;
    const int rb_hi = wid * 16 + 128;
    loadA(w_hh0, rb_lo, lane, Ahi0[0], Alo0[0], Ahi1[0], Alo1[0]);
    loadA(w_hh0, rb_hi, lane, Ahi0[1], Alo0[1], Ahi1[1], Alo1[1]);
    loadA(w_ih1, rb_lo, lane, Ahi0[2], Alo0[2], Ahi1[2], Alo1[2]);
    loadA(w_ih1, rb_hi, lane, Ahi0[3], Alo0[3], Ahi1[3], Alo1[3]);
    loadA(w_hh1, rb_lo, lane, Ahi0[4], Alo0[4], Ahi1[4], Alo1[4]);
    loadA(w_hh1, rb_hi, lane, Ahi0[5], Alo0[5], Ahi1[5], Alo1[5]);

    // ---- bias fragments (C/D layout: row = q*4+r, col = r15) ----
    f32x4 biasf[6];
    #pragma unroll
    for (int j = 0; j < 6; ++j) {
        const int rb = (wid + 8 * (j & 1)) * 16 + q * 4;
        #pragma unroll
        for (int r = 0; r < 4; ++r) {
            float bv = 0.f;
            if (j < 2)      bv = b_ih0[rb + r] + b_hh0[rb + r];
            else if (j < 4) bv = b_ih1[rb + r] + b_hh1[rb + r];
            biasf[j][r] = bv;
        }
    }

    // ---- update-phase ownership: thread -> (b, k), both layers ----
    const int ub = tid >> 6;      // batch 0..7 (== wid)
    const int uk = tid & 63;      // hidden unit
    const float wx0 = w_ih0[uk];
    const float wx1 = w_ih0[64  + uk];
    const float wx2 = w_ih0[128 + uk];
    const float wx3 = w_ih0[192 + uk];
    float c1 = 0.f, c2 = 0.f;

    __syncthreads();

    // Skewed pipeline: iteration i computes L0 gates(step i) and L1 gates(step i-1).
    for (int i = 0; i <= TLEN; ++i) {
        // ======== MFMA phase ========
        // B fragments: lane l supplies B[khalf*32 + q*8 + e][r15] = h[r15][k]
        const bf16x8 B1h0 = *(const bf16x8*)&h1hi[r15][q * 8];
        const bf16x8 B1h1 = *(const bf16x8*)&h1hi[r15][32 + q * 8];
        const bf16x8 B1l0 = *(const bf16x8*)&h1lo[r15][q * 8];
        const bf16x8 B1l1 = *(const bf16x8*)&h1lo[r15][32 + q * 8];
        const bf16x8 B2h0 = *(const bf16x8*)&h2hi[r15][q * 8];
        const bf16x8 B2h1 = *(const bf16x8*)&h2hi[r15][32 + q * 8];
        const bf16x8 B2l0 = *(const bf16x8*)&h2lo[r15][q * 8];
        const bf16x8 B2l1 = *(const bf16x8*)&h2lo[r15][32 + q * 8];

        #pragma unroll
        for (int j = 0; j < 6; ++j) {
            const bf16x8 bh0 = (j < 4) ? B1h0 : B2h0;   // j static -> folds
            const bf16x8 bh1 = (j < 4) ? B1h1 : B2h1;
            const bf16x8 bl0 = (j < 4) ? B1l0 : B2l0;
            const bf16x8 bl1 = (j < 4) ? B1l1 : B2l1;
            f32x4 acc = biasf[j];
            acc = __builtin_amdgcn_mfma_f32_16x16x32_bf16(Ahi0[j], bh0, acc, 0, 0, 0);
            acc = __builtin_amdgcn_mfma_f32_16x16x32_bf16(Ahi1[j], bh1, acc, 0, 0, 0);
            acc = __builtin_amdgcn_mfma_f32_16x16x32_bf16(Alo0[j], bh0, acc, 0, 0, 0);
            acc = __builtin_amdgcn_mfma_f32_16x16x32_bf16(Alo1[j], bh1, acc, 0, 0, 0);
            acc = __builtin_amdgcn_mfma_f32_16x16x32_bf16(Ahi0[j], bl0, acc, 0, 0, 0);
            acc = __builtin_amdgcn_mfma_f32_16x16x32_bf16(Ahi1[j], bl1, acc, 0, 0, 0);
            acc = __builtin_amdgcn_mfma_f32_16x16x32_bf16(Alo0[j], bl0, acc, 0, 0, 0);
            acc = __builtin_amdgcn_mfma_f32_16x16x32_bf16(Alo1[j], bl1, acc, 0, 0, 0);
            // D: row = q*4+r, col = r15; only cols 0..7 are real batches
            if (r15 < NB) {
                const int growbase = (j >> 1) * 256 + (wid + 8 * (j & 1)) * 16 + q * 4;
                #pragma unroll
                for (int r = 0; r < 4; ++r)
                    gates[(growbase + r) * 9 + r15] = acc[r];
            }
        }
        __syncthreads();

        // ======== update phase ========
        if (i < TLEN) {   // layer 0, step i
            const float xv = xs[ub][i];
            const float p0 = gates[(      uk) * 9 + ub] + wx0 * xv;
            const float p1 = gates[( 64 + uk) * 9 + ub] + wx1 * xv;
            const float p2 = gates[(128 + uk) * 9 + ub] + wx2 * xv;
            const float p3 = gates[(192 + uk) * 9 + ub] + wx3 * xv;
            const float gi = sigm(p0), gf = sigm(p1), gg = tanh_(p2), go = sigm(p3);
            c1 = fmaf(gf, c1, gi * gg);
            const float h1v = go * tanh_(c1);
            const short hh = bf16rn(h1v);
            h1hi[ub][uk] = hh;
            h1lo[ub][uk] = bf16rn(h1v - bf2f(hh));
        }
        if (i >= 1) {     // layer 1, step i-1 (bias1 already in mat1 acc init)
            const float p0 = gates[(256 +       uk) * 9 + ub] + gates[(512 +       uk) * 9 + ub];
            const float p1 = gates[(256 +  64 + uk) * 9 + ub] + gates[(512 +  64 + uk) * 9 + ub];
            const float p2 = gates[(256 + 128 + uk) * 9 + ub] + gates[(512 + 128 + uk) * 9 + ub];
            const float p3 = gates[(256 + 192 + uk) * 9 + ub] + gates[(512 + 192 + uk) * 9 + ub];
            const float gi = sigm(p0), gf = sigm(p1), gg = tanh_(p2), go = sigm(p3);
            c2 = fmaf(gf, c2, gi * gg);
            const float h2v = go * tanh_(c2);
            const short hh = bf16rn(h2v);
            h2hi[ub][uk] = hh;
            h2lo[ub][uk] = bf16rn(h2v - bf2f(hh));
            if (i == TLEN) h2last[ub * HDIM + uk] = h2v;
        }
        __syncthreads();
    }

    // ======== final FC: wave w reduces batch w ========
    {
        float p = fc_w[uk] * h2last[ub * HDIM + uk];
        #pragma unroll
        for (int off = 32; off; off >>= 1) p += __shfl_down(p, off, 64);
        if (uk == 0) out[b0 + ub] = p + fc_b[0];
    }
}

extern "C" void kernel_launch(void* const* d_in, const int* in_sizes, int n_in,
                              void* d_out, int out_size, void* d_ws, size_t ws_size,
                              hipStream_t stream) {
    const float* xp     = (const float*)d_in[0];
    const float* w_ih0  = (const float*)d_in[1];
    const float* w_hh0  = (const float*)d_in[2];
    const float* b_ih0  = (const float*)d_in[3];
    const float* b_hh0  = (const float*)d_in[4];
    const float* w_ih1  = (const float*)d_in[5];
    const float* w_hh1  = (const float*)d_in[6];
    const float* b_ih1  = (const float*)d_in[7];
    const float* b_hh1  = (const float*)d_in[8];
    const float* fc_w   = (const float*)d_in[9];
    const float* fc_b   = (const float*)d_in[10];
    float* outp = (float*)d_out;

    lstm2_mfma<<<dim3(GRID), dim3(NTH), 0, stream>>>(
        xp, w_ih0, w_hh0, b_ih0, b_hh0,
        w_ih1, w_hh1, b_ih1, b_hh1, fc_w, fc_b, outp);
}